// Round 6
// baseline (546.052 us; speedup 1.0000x reference)
//
#include <hip/hip_runtime.h>
#include <math.h>

#define B_ 4
#define N_ 256
#define D_ 128
#define H_ 256
#define K_ 8
#define NH 512    // both nets' hidden concat (g: 0..255, a: 256..511)
#define KK 256    // GEMM K = [p (128) | sj (128)]
#define NJP 64    // j per phase (4 phases)
#define LDA 264   // LDS A-tile row stride in bf16 elems (16B-aligned rows)

typedef short v8s __attribute__((ext_vector_type(8)));    // 8 bf16 = 4 VGPRs
typedef float v16f __attribute__((ext_vector_type(16)));  // 32x32 MFMA acc

// hi = top-16-bit truncation (x - hi is EXACT); lo = RNE bf16 of remainder.
__device__ inline void split_bf16(float x, unsigned short& hi, unsigned short& lo) {
  unsigned u = __float_as_uint(x);
  unsigned uh = u & 0xFFFF0000u;
  hi = (unsigned short)(uh >> 16);
  float r = x - __uint_as_float(uh);
  unsigned ur = __float_as_uint(r);
  ur += 0x7FFFu + ((ur >> 16) & 1u);
  lo = (unsigned short)(ur >> 16);
}

__global__ __launch_bounds__(256) void prep_an(
    const float* __restrict__ s,
    const float* __restrict__ Wg1, const float* __restrict__ bg1,
    const float* __restrict__ Wa1, const float* __restrict__ ba1,
    float* __restrict__ Ag, float* __restrict__ Aa,
    unsigned short* __restrict__ Shi, unsigned short* __restrict__ Slo) {
  const int b = blockIdx.x >> 8;
  const int n = blockIdx.x & 255;
  const int h = threadIdx.x;
  __shared__ float sh[D_];
  if (h < D_) sh[h] = s[(b * N_ + n) * D_ + h];
  __syncthreads();
  float ag = bg1[h], aa = ba1[h];
#pragma unroll 8
  for (int d = 0; d < D_; d++) {
    ag = fmaf(sh[d], Wg1[d * H_ + h], ag);
    aa = fmaf(sh[d], Wa1[d * H_ + h], aa);
  }
  Ag[(b * N_ + n) * H_ + h] = ag;
  Aa[(b * N_ + n) * H_ + h] = aa;
  if (h < D_) {
    unsigned short x, y;
    split_bf16(sh[h], x, y);
    Shi[(b * N_ + n) * D_ + h] = x;
    Slo[(b * N_ + n) * D_ + h] = y;
  }
}

__global__ __launch_bounds__(256) void prep_w(
    const float* __restrict__ Wg1, const float* __restrict__ Wa1,
    unsigned short* __restrict__ Whi, unsigned short* __restrict__ Wlo) {
  const int h = blockIdx.x;       // 0..511
  const int k = threadIdx.x;      // 0..255
  const float* src = (h < H_) ? Wg1 : Wa1;
  const int hh = h & (H_ - 1);
  const int f = (k < D_) ? (2 * D_ + k) : k;
  float w = src[f * H_ + hh];
  unsigned short x, y;
  split_bf16(w, x, y);
  Whi[h * KK + k] = x;
  Wlo[h * KK + k] = y;
}

__device__ inline void arg_better(float v2, int i2, float& v, int& idx) {
  if (v2 > v || (v2 == v && i2 < idx)) { v = v2; idx = i2; }
}

// ---------------------------------------------------------------------------
// score_kernel v6: 32x32x16 MFMA; gate = split-3 (exact top-k), att = plain
// bf16 (softmax tolerates 1e-3). Whole-ks ping-pong of A(LDS)+B(global) regs.
// ---------------------------------------------------------------------------
__global__ __launch_bounds__(256, 2) void score_kernel(
    const float* __restrict__ s,
    const float* __restrict__ Ag, const float* __restrict__ Aa,
    const unsigned short* __restrict__ Shi, const unsigned short* __restrict__ Slo,
    const unsigned short* __restrict__ Whi, const unsigned short* __restrict__ Wlo,
    const float* __restrict__ Wg2, const float* __restrict__ bg2p,
    const float* __restrict__ Wa2, const float* __restrict__ ba2p,
    float* __restrict__ out) {
  const int b = blockIdx.x >> 8;
  const int i = blockIdx.x & 255;
  const int t = threadIdx.x;
  const int wv = t >> 6, lane = t & 63;
  const int m32 = lane & 31, half32 = lane >> 5;

  __shared__ unsigned short a_hi[NJP * LDA];   // A tile hi (33792 B)
  __shared__ unsigned short a_lo[NJP * LDA];   // A tile lo
  __shared__ float si_sh[D_];
  __shared__ float agaa_sh[NH];
  __shared__ float w2_sh[NH];
  __shared__ float sc_part[8 * NJP];           // [0..3]=gate per wave, [4..7]=att
  __shared__ float scg_sh[N_];
  __shared__ float attl_sh[N_];
  __shared__ float red_v[4];
  __shared__ int red_i[4];
  __shared__ int sel_list[K_];

  if (t < D_) si_sh[t] = s[(b * N_ + i) * D_ + t];
  agaa_sh[t] = Ag[(b * N_ + i) * H_ + t];
  agaa_sh[H_ + t] = Aa[(b * N_ + i) * H_ + t];
  w2_sh[t] = Wg2[t];
  w2_sh[H_ + t] = Wa2[t];

  // B-frag base pointers: n-row = h, k-offset = half32*8 (+ks*16 imm)
  const unsigned short* __restrict__ wgh[2];
  const unsigned short* __restrict__ wgl[2];
  const unsigned short* __restrict__ wah[2];
#pragma unroll
  for (int ht = 0; ht < 2; ht++) {
    const int hg = wv * 64 + ht * 32 + m32;         // gate h (W rows 0..255)
    const int ha = 256 + wv * 64 + ht * 32 + m32;   // att h (W rows 256..511)
    wgh[ht] = Whi + hg * KK + half32 * 8;
    wgl[ht] = Wlo + hg * KK + half32 * 8;
    wah[ht] = Whi + ha * KK + half32 * 8;
  }

#pragma unroll 1
  for (int ph = 0; ph < 4; ph++) {
    __syncthreads();
    // ---- stage A tile: P hi/lo (k<128) + sj hi/lo (k>=128) ----
    {
      const int jl = t >> 2, kq = t & 3;
      const int jg = b * N_ + ph * NJP + jl;
      const float* srow = s + jg * D_ + kq * 32;
      const float* sic = si_sh + kq * 32;
      unsigned short* rh = a_hi + jl * LDA + kq * 32;
      unsigned short* rl = a_lo + jl * LDA + kq * 32;
#pragma unroll
      for (int u = 0; u < 8; u++) {
        const float4 sv = *(const float4*)(srow + u * 4);
        unsigned short h0, h1, h2, h3, l0, l1, l2, l3;
        split_bf16(sic[u * 4 + 0] * sv.x, h0, l0);
        split_bf16(sic[u * 4 + 1] * sv.y, h1, l1);
        split_bf16(sic[u * 4 + 2] * sv.z, h2, l2);
        split_bf16(sic[u * 4 + 3] * sv.w, h3, l3);
        *(unsigned*)(rh + u * 4)     = (unsigned)h0 | ((unsigned)h1 << 16);
        *(unsigned*)(rh + u * 4 + 2) = (unsigned)h2 | ((unsigned)h3 << 16);
        *(unsigned*)(rl + u * 4)     = (unsigned)l0 | ((unsigned)l1 << 16);
        *(unsigned*)(rl + u * 4 + 2) = (unsigned)l2 | ((unsigned)l3 << 16);
      }
      const unsigned short* shr = Shi + jg * D_ + kq * 32;
      const unsigned short* slr = Slo + jg * D_ + kq * 32;
#pragma unroll
      for (int u = 0; u < 4; u++) {
        *(v8s*)(rh + 128 + u * 8) = *(const v8s*)(shr + u * 8);
        *(v8s*)(rl + 128 + u * 8) = *(const v8s*)(slr + u * 8);
      }
    }
    __syncthreads();

    // ---- GEMM M=64 x N=(256g+256a) x K=256, 32x32x16, ping-pong ----
    v16f accg[2][2], acca[2][2];
#pragma unroll
    for (int jt = 0; jt < 2; jt++)
#pragma unroll
      for (int ht = 0; ht < 2; ht++) {
        accg[jt][ht] = (v16f)(0.f);
        acca[jt][ht] = (v16f)(0.f);
      }

    v8s bgh[2][2], bgl[2][2], bah[2][2];   // [buf][ht]
    v8s ahr[2][2], alr[2][2];              // [buf][jt]
#pragma unroll
    for (int ht = 0; ht < 2; ht++) {       // preload ks=0
      bgh[0][ht] = *(const v8s*)(wgh[ht]);
      bgl[0][ht] = *(const v8s*)(wgl[ht]);
      bah[0][ht] = *(const v8s*)(wah[ht]);
    }
#pragma unroll
    for (int jt = 0; jt < 2; jt++) {
      ahr[0][jt] = *(const v8s*)(a_hi + (jt * 32 + m32) * LDA + half32 * 8);
      alr[0][jt] = *(const v8s*)(a_lo + (jt * 32 + m32) * LDA + half32 * 8);
    }

#pragma unroll
    for (int ks = 0; ks < 16; ks++) {
      const int cur = ks & 1, nxt = cur ^ 1;
      const int kn = ((ks + 1) & 15) * 16;   // shorts (wraps; last redundant)
      // prefetch B for ks+1
#pragma unroll
      for (int ht = 0; ht < 2; ht++) {
        bgh[nxt][ht] = *(const v8s*)(wgh[ht] + kn);
        bgl[nxt][ht] = *(const v8s*)(wgl[ht] + kn);
        bah[nxt][ht] = *(const v8s*)(wah[ht] + kn);
      }
      // prefetch A for ks+1
#pragma unroll
      for (int jt = 0; jt < 2; jt++) {
        ahr[nxt][jt] = *(const v8s*)(a_hi + (jt * 32 + m32) * LDA + kn + half32 * 8);
        alr[nxt][jt] = *(const v8s*)(a_lo + (jt * 32 + m32) * LDA + kn + half32 * 8);
      }
      // compute current ks
#pragma unroll
      for (int ht = 0; ht < 2; ht++)
#pragma unroll
        for (int jt = 0; jt < 2; jt++) {
          accg[jt][ht] = __builtin_amdgcn_mfma_f32_32x32x16_bf16(
              ahr[cur][jt], bgh[cur][ht], accg[jt][ht], 0, 0, 0);
          accg[jt][ht] = __builtin_amdgcn_mfma_f32_32x32x16_bf16(
              ahr[cur][jt], bgl[cur][ht], accg[jt][ht], 0, 0, 0);
          accg[jt][ht] = __builtin_amdgcn_mfma_f32_32x32x16_bf16(
              alr[cur][jt], bgh[cur][ht], accg[jt][ht], 0, 0, 0);
          acca[jt][ht] = __builtin_amdgcn_mfma_f32_32x32x16_bf16(
              ahr[cur][jt], bah[cur][ht], acca[jt][ht], 0, 0, 0);
        }
    }

    // ---- epilogue: relu + W2 dot, butterfly over the 32 h-lanes ----
    float sg[32], sa[32];   // [jt*16 + r]
#pragma unroll
    for (int m = 0; m < 32; m++) { sg[m] = 0.f; sa[m] = 0.f; }
#pragma unroll
    for (int ht = 0; ht < 2; ht++) {
      const int hg = wv * 64 + ht * 32 + m32;
      const int ha = 256 + wv * 64 + ht * 32 + m32;
      const float agv = agaa_sh[hg], w2g = w2_sh[hg];
      const float aav = agaa_sh[ha], w2a = w2_sh[ha];
#pragma unroll
      for (int jt = 0; jt < 2; jt++)
#pragma unroll
        for (int r = 0; r < 16; r++) {
          const float zg = accg[jt][ht][r] + agv;
          sg[jt * 16 + r] = fmaf(fmaxf(zg, 0.f), w2g, sg[jt * 16 + r]);
          const float za = acca[jt][ht][r] + aav;
          sa[jt * 16 + r] = fmaf(fmaxf(za, 0.f), w2a, sa[jt * 16 + r]);
        }
    }
#pragma unroll
    for (int m = 0; m < 32; m++) {
      float vg = sg[m], va = sa[m];
#pragma unroll
      for (int off = 1; off <= 16; off <<= 1) {
        vg += __shfl_xor(vg, off, 64);
        va += __shfl_xor(va, off, 64);
      }
      sg[m] = vg; sa[m] = va;
    }
    if (m32 == 0) {
#pragma unroll
      for (int jt = 0; jt < 2; jt++)
#pragma unroll
        for (int r = 0; r < 16; r++) {
          const int jl = jt * 32 + (r & 3) + 8 * (r >> 2) + 4 * half32;
          sc_part[wv * NJP + jl] = sg[jt * 16 + r];
          sc_part[4 * NJP + wv * NJP + jl] = sa[jt * 16 + r];
        }
    }
    __syncthreads();
    if (t < NJP) {
      scg_sh[ph * NJP + t] = sc_part[t] + sc_part[NJP + t] + sc_part[2 * NJP + t]
                           + sc_part[3 * NJP + t] + bg2p[0];
      attl_sh[ph * NJP + t] = sc_part[4 * NJP + t] + sc_part[5 * NJP + t]
                            + sc_part[6 * NJP + t] + sc_part[7 * NJP + t] + ba2p[0];
    }
  }
  __syncthreads();

  // ---- top-8 over j: value desc, index asc ----
  for (int k = 0; k < K_; k++) {
    float v = scg_sh[t];
    int idx = t;
#pragma unroll
    for (int off = 32; off > 0; off >>= 1) {
      const float vo = __shfl_down(v, off, 64);
      const int io = __shfl_down(idx, off, 64);
      arg_better(vo, io, v, idx);
    }
    if ((t & 63) == 0) { red_v[t >> 6] = v; red_i[t >> 6] = idx; }
    __syncthreads();
    if (t == 0) {
      float bv = red_v[0];
      int bi = red_i[0];
      for (int w = 1; w < 4; w++) arg_better(red_v[w], red_i[w], bv, bi);
      sel_list[k] = bi;
      scg_sh[bi] = -INFINITY;
    }
    __syncthreads();
  }

  bool selj = false;
#pragma unroll
  for (int k = 0; k < K_; k++) selj = selj || (sel_list[k] == t);

  if (t == 0) {
    float m = -INFINITY;
    for (int k = 0; k < K_; k++) m = fmaxf(m, attl_sh[sel_list[k]]);
    float ssum = 0.f;
    for (int k = 0; k < K_; k++) ssum += expf(attl_sh[sel_list[k]] - m);
    red_v[0] = m;
    red_v[1] = ssum;
  }
  __syncthreads();
  const float att = selj ? expf(attl_sh[t] - red_v[0]) / red_v[1] : 0.f;

  float* __restrict__ ctx_out = out;
  float* __restrict__ gate_out = out + B_ * N_ * D_;
  float* __restrict__ att_out = out + B_ * N_ * D_ + B_ * N_ * N_;

  const int row = (b * N_ + i) * N_;
  gate_out[row + t] = selj ? 1.f : 0.f;
  att_out[row + t] = att;

  __syncthreads();
  attl_sh[t] = att;
  __syncthreads();

  if (t < D_) {
    float acc2 = 0.f;
#pragma unroll
    for (int k = 0; k < K_; k++) {
      const int jj = sel_list[k];
      acc2 = fmaf(attl_sh[jj], s[(b * N_ + jj) * D_ + t], acc2);
    }
    ctx_out[(b * N_ + i) * D_ + t] = acc2;
  }
}

extern "C" void kernel_launch(void* const* d_in, const int* in_sizes, int n_in,
                              void* d_out, int out_size, void* d_ws, size_t ws_size,
                              hipStream_t stream) {
  const float* s   = (const float*)d_in[0];
  const float* Wg1 = (const float*)d_in[1];
  const float* bg1 = (const float*)d_in[2];
  const float* Wg2 = (const float*)d_in[3];
  const float* bg2 = (const float*)d_in[4];
  const float* Wa1 = (const float*)d_in[5];
  const float* ba1 = (const float*)d_in[6];
  const float* Wa2 = (const float*)d_in[7];
  const float* ba2 = (const float*)d_in[8];
  float* out = (float*)d_out;

  float* ws = (float*)d_ws;
  float* Ag = ws;
  float* Aa = Ag + B_ * N_ * H_;
  unsigned short* Whi = (unsigned short*)(Aa + B_ * N_ * H_);
  unsigned short* Wlo = Whi + NH * KK;
  unsigned short* Shi = Wlo + NH * KK;
  unsigned short* Slo = Shi + B_ * N_ * D_;

  prep_an<<<dim3(B_ * N_), dim3(256), 0, stream>>>(
      s, Wg1, bg1, Wa1, ba1, Ag, Aa, Shi, Slo);
  prep_w<<<dim3(NH), dim3(256), 0, stream>>>(Wg1, Wa1, Whi, Wlo);
  score_kernel<<<dim3(B_ * N_), dim3(256), 0, stream>>>(
      s, Ag, Aa, Shi, Slo, Whi, Wlo, Wg2, bg2, Wa2, ba2, out);
}

// Round 7
// 389.464 us; speedup vs baseline: 1.4021x; 1.4021x over previous
//
#include <hip/hip_runtime.h>
#include <math.h>

#define B_ 4
#define N_ 256
#define D_ 128
#define H_ 256
#define K_ 8
#define KK 256    // GEMM K = [p (128) | sj (128)]
#define NJP 64    // j per phase (4 phases)

typedef short v8s __attribute__((ext_vector_type(8)));    // 8 bf16 = 4 VGPRs
typedef float v16f __attribute__((ext_vector_type(16)));  // 32x32 MFMA acc

// hi = top-16-bit truncation (x - hi is EXACT); lo = RNE bf16 of remainder.
__device__ inline void split_bf16(float x, unsigned short& hi, unsigned short& lo) {
  unsigned u = __float_as_uint(x);
  unsigned uh = u & 0xFFFF0000u;
  hi = (unsigned short)(uh >> 16);
  float r = x - __uint_as_float(uh);
  unsigned ur = __float_as_uint(r);
  ur += 0x7FFFu + ((ur >> 16) & 1u);
  lo = (unsigned short)(ur >> 16);
}

__global__ __launch_bounds__(256) void prep_an(
    const float* __restrict__ s,
    const float* __restrict__ Wg1, const float* __restrict__ bg1,
    const float* __restrict__ Wa1, const float* __restrict__ ba1,
    float* __restrict__ Ag, float* __restrict__ Aa,
    unsigned short* __restrict__ Shi, unsigned short* __restrict__ Slo) {
  const int b = blockIdx.x >> 8;
  const int n = blockIdx.x & 255;
  const int h = threadIdx.x;
  __shared__ float sh[D_];
  if (h < D_) sh[h] = s[(b * N_ + n) * D_ + h];
  __syncthreads();
  float ag = bg1[h], aa = ba1[h];
#pragma unroll 8
  for (int d = 0; d < D_; d++) {
    ag = fmaf(sh[d], Wg1[d * H_ + h], ag);
    aa = fmaf(sh[d], Wa1[d * H_ + h], aa);
  }
  Ag[(b * N_ + n) * H_ + h] = ag;
  Aa[(b * N_ + n) * H_ + h] = aa;
  if (h < D_) {
    unsigned short x, y;
    split_bf16(sh[h], x, y);
    Shi[(b * N_ + n) * D_ + h] = x;
    Slo[(b * N_ + n) * D_ + h] = y;
  }
}

// ---------------------------------------------------------------------------
// prep_sw: W in MFMA-B fragment order: [ks(16)][tile(8 of 32h)][lane(64)][8].
// Lane l of a wave covering h-tile T at k-step ks loads 16 B at
// ((ks*8+T)*64+l)*8 — fully coalesced (16 cache lines/instr vs 64 for the
// naive [h][k] gather, which was v5/v6's hidden VMEM bottleneck).
// Fragment content: h = T*32 + (l&31), k = ks*16 + (l>>5)*8 + e.
// k<128 -> W1 row 256+k (P part); k>=128 -> W1 row k (sj part).
// ---------------------------------------------------------------------------
__global__ __launch_bounds__(64) void prep_sw(
    const float* __restrict__ Wg1, const float* __restrict__ Wa1,
    unsigned short* __restrict__ Wghi, unsigned short* __restrict__ Wglo,
    unsigned short* __restrict__ Wahi) {
  const int ks = blockIdx.x >> 3;
  const int tile = blockIdx.x & 7;
  const int lane = threadIdx.x;
  const int h = tile * 32 + (lane & 31);
  const int kbase = ks * 16 + (lane >> 5) * 8;
  const int idx0 = (blockIdx.x * 64 + lane) * 8;
#pragma unroll
  for (int e = 0; e < 8; e++) {
    const int k = kbase + e;
    const int f = (k < D_) ? (2 * D_ + k) : k;
    unsigned short x, y;
    split_bf16(Wg1[f * H_ + h], x, y);
    Wghi[idx0 + e] = x;
    Wglo[idx0 + e] = y;
    unsigned short xa, ya;
    split_bf16(Wa1[f * H_ + h], xa, ya);
    Wahi[idx0 + e] = xa;
  }
}

__device__ inline void arg_better(float v2, int i2, float& v, int& idx) {
  if (v2 > v || (v2 == v && i2 < idx)) { v = v2; idx = i2; }
}

// LDS A-tile fragment-order index: j-local jl (0..63), k (0..255)
__device__ inline int a_idx(int jl, int k) {
  return (((jl >> 5) * 16 + (k >> 4)) * 64 + ((k >> 3) & 1) * 32 + (jl & 31)) * 8
         + (k & 7);
}

// ---------------------------------------------------------------------------
// score_kernel v7: 32x32x16 MFMA. Per phase (64 j): stage A (P hi/lo + sj)
// in LDS in FRAGMENT ORDER (conflict-free ds_read_b128), then two K-passes
// sharing acc regs: gate (split-3) then att (hi-only). B streams from the
// pre-swizzled global arrays with whole-ks register ping-pong.
// ---------------------------------------------------------------------------
__global__ __launch_bounds__(256, 2) void score_kernel(
    const float* __restrict__ s,
    const float* __restrict__ Ag, const float* __restrict__ Aa,
    const unsigned short* __restrict__ Shi, const unsigned short* __restrict__ Slo,
    const unsigned short* __restrict__ Wghi, const unsigned short* __restrict__ Wglo,
    const unsigned short* __restrict__ Wahi,
    const float* __restrict__ Wg2, const float* __restrict__ bg2p,
    const float* __restrict__ Wa2, const float* __restrict__ ba2p,
    float* __restrict__ out) {
  const int b = blockIdx.x >> 8;
  const int i = blockIdx.x & 255;
  const int t = threadIdx.x;
  const int wv = t >> 6, lane = t & 63;
  const int m32 = lane & 31, half32 = lane >> 5;

  __shared__ unsigned short a_hi[2 * 16 * 64 * 8];   // 32 KB, frag order
  __shared__ unsigned short a_lo[2 * 16 * 64 * 8];   // 32 KB
  __shared__ float si_sh[D_];
  __shared__ float agaa_sh[2 * H_];
  __shared__ float w2_sh[2 * H_];
  __shared__ float sc_part[8 * NJP];   // [0..3]=gate per wave, [4..7]=att
  __shared__ float scg_sh[N_];
  __shared__ float attl_sh[N_];
  __shared__ float red_v[4];
  __shared__ int red_i[4];
  __shared__ int sel_list[K_];

  if (t < D_) si_sh[t] = s[(b * N_ + i) * D_ + t];
  agaa_sh[t] = Ag[(b * N_ + i) * H_ + t];
  agaa_sh[H_ + t] = Aa[(b * N_ + i) * H_ + t];
  w2_sh[t] = Wg2[t];
  w2_sh[H_ + t] = Wa2[t];

  // B fragment pointers: wave wv covers h-tiles {2wv, 2wv+1}; +ks*4096 shorts
  const unsigned short* __restrict__ wgh[2];
  const unsigned short* __restrict__ wgl[2];
  const unsigned short* __restrict__ wah[2];
#pragma unroll
  for (int ht = 0; ht < 2; ht++) {
    const int off = ((2 * wv + ht) * 64 + lane) * 8;
    wgh[ht] = Wghi + off;
    wgl[ht] = Wglo + off;
    wah[ht] = Wahi + off;
  }

#pragma unroll 1
  for (int ph = 0; ph < 4; ph++) {
    __syncthreads();
    // ---- stage A tile (frag order): P hi/lo (k<128) + sj hi/lo (k>=128) ----
    {
      const int jl = t >> 2, kq = t & 3;
      const int jg = b * N_ + ph * NJP + jl;
      const float* srow = s + jg * D_ + kq * 32;
      const float* sic = si_sh + kq * 32;
#pragma unroll
      for (int u = 0; u < 8; u++) {
        const float4 sv = *(const float4*)(srow + u * 4);
        unsigned short h0, h1, h2, h3, l0, l1, l2, l3;
        split_bf16(sic[u * 4 + 0] * sv.x, h0, l0);
        split_bf16(sic[u * 4 + 1] * sv.y, h1, l1);
        split_bf16(sic[u * 4 + 2] * sv.z, h2, l2);
        split_bf16(sic[u * 4 + 3] * sv.w, h3, l3);
        const int idx = a_idx(jl, kq * 32 + u * 4);
        *(unsigned*)(a_hi + idx)     = (unsigned)h0 | ((unsigned)h1 << 16);
        *(unsigned*)(a_hi + idx + 2) = (unsigned)h2 | ((unsigned)h3 << 16);
        *(unsigned*)(a_lo + idx)     = (unsigned)l0 | ((unsigned)l1 << 16);
        *(unsigned*)(a_lo + idx + 2) = (unsigned)l2 | ((unsigned)l3 << 16);
      }
      const unsigned short* shr = Shi + jg * D_ + kq * 32;
      const unsigned short* slr = Slo + jg * D_ + kq * 32;
#pragma unroll
      for (int u = 0; u < 4; u++) {
        const int idx = a_idx(jl, 128 + kq * 32 + u * 8);
        *(v8s*)(a_hi + idx) = *(const v8s*)(shr + u * 8);
        *(v8s*)(a_lo + idx) = *(const v8s*)(slr + u * 8);
      }
    }
    __syncthreads();

    // ================= pass G: gate (split-3), acc 64 regs =================
    {
      v16f acc[2][2];
#pragma unroll
      for (int jt = 0; jt < 2; jt++)
#pragma unroll
        for (int ht = 0; ht < 2; ht++) acc[jt][ht] = (v16f)(0.f);

      v8s bh[2][2], bl[2][2], ah[2][2], al[2][2];
#pragma unroll
      for (int ht = 0; ht < 2; ht++) {
        bh[0][ht] = *(const v8s*)(wgh[ht]);
        bl[0][ht] = *(const v8s*)(wgl[ht]);
      }
#pragma unroll
      for (int jt = 0; jt < 2; jt++) {
        ah[0][jt] = *(const v8s*)(a_hi + (jt * 16) * 512 + lane * 8);
        al[0][jt] = *(const v8s*)(a_lo + (jt * 16) * 512 + lane * 8);
      }
#pragma unroll
      for (int ks = 0; ks < 16; ks++) {
        const int cur = ks & 1, nxt = cur ^ 1;
        const int kn = (ks + 1) & 15;
#pragma unroll
        for (int ht = 0; ht < 2; ht++) {
          bh[nxt][ht] = *(const v8s*)(wgh[ht] + kn * 4096);
          bl[nxt][ht] = *(const v8s*)(wgl[ht] + kn * 4096);
        }
#pragma unroll
        for (int jt = 0; jt < 2; jt++) {
          ah[nxt][jt] = *(const v8s*)(a_hi + (jt * 16 + kn) * 512 + lane * 8);
          al[nxt][jt] = *(const v8s*)(a_lo + (jt * 16 + kn) * 512 + lane * 8);
        }
#pragma unroll
        for (int ht = 0; ht < 2; ht++)
#pragma unroll
          for (int jt = 0; jt < 2; jt++) {
            acc[jt][ht] = __builtin_amdgcn_mfma_f32_32x32x16_bf16(
                ah[cur][jt], bh[cur][ht], acc[jt][ht], 0, 0, 0);
            acc[jt][ht] = __builtin_amdgcn_mfma_f32_32x32x16_bf16(
                ah[cur][jt], bl[cur][ht], acc[jt][ht], 0, 0, 0);
            acc[jt][ht] = __builtin_amdgcn_mfma_f32_32x32x16_bf16(
                al[cur][jt], bh[cur][ht], acc[jt][ht], 0, 0, 0);
          }
      }
      // epilogue G
      float sg[32];
#pragma unroll
      for (int m = 0; m < 32; m++) sg[m] = 0.f;
#pragma unroll
      for (int ht = 0; ht < 2; ht++) {
        const int hg = wv * 64 + ht * 32 + m32;
        const float agv = agaa_sh[hg], w2g = w2_sh[hg];
#pragma unroll
        for (int jt = 0; jt < 2; jt++)
#pragma unroll
          for (int r = 0; r < 16; r++) {
            const float z = acc[jt][ht][r] + agv;
            sg[jt * 16 + r] = fmaf(fmaxf(z, 0.f), w2g, sg[jt * 16 + r]);
          }
      }
#pragma unroll
      for (int m = 0; m < 32; m++) {
        float v = sg[m];
#pragma unroll
        for (int off = 1; off <= 16; off <<= 1) v += __shfl_xor(v, off, 64);
        sg[m] = v;
      }
      if (m32 == 0) {
#pragma unroll
        for (int jt = 0; jt < 2; jt++)
#pragma unroll
          for (int r = 0; r < 16; r++) {
            const int jl = jt * 32 + (r & 3) + 8 * (r >> 2) + 4 * half32;
            sc_part[wv * NJP + jl] = sg[jt * 16 + r];
          }
      }
    }

    // ================= pass A: att (hi-only), acc 64 regs =================
    {
      v16f acc[2][2];
#pragma unroll
      for (int jt = 0; jt < 2; jt++)
#pragma unroll
        for (int ht = 0; ht < 2; ht++) acc[jt][ht] = (v16f)(0.f);

      v8s bh[2][2], ah[2][2];
#pragma unroll
      for (int ht = 0; ht < 2; ht++) bh[0][ht] = *(const v8s*)(wah[ht]);
#pragma unroll
      for (int jt = 0; jt < 2; jt++)
        ah[0][jt] = *(const v8s*)(a_hi + (jt * 16) * 512 + lane * 8);
#pragma unroll
      for (int ks = 0; ks < 16; ks++) {
        const int cur = ks & 1, nxt = cur ^ 1;
        const int kn = (ks + 1) & 15;
#pragma unroll
        for (int ht = 0; ht < 2; ht++)
          bh[nxt][ht] = *(const v8s*)(wah[ht] + kn * 4096);
#pragma unroll
        for (int jt = 0; jt < 2; jt++)
          ah[nxt][jt] = *(const v8s*)(a_hi + (jt * 16 + kn) * 512 + lane * 8);
#pragma unroll
        for (int ht = 0; ht < 2; ht++)
#pragma unroll
          for (int jt = 0; jt < 2; jt++)
            acc[jt][ht] = __builtin_amdgcn_mfma_f32_32x32x16_bf16(
                ah[cur][jt], bh[cur][ht], acc[jt][ht], 0, 0, 0);
      }
      // epilogue A
      float sa[32];
#pragma unroll
      for (int m = 0; m < 32; m++) sa[m] = 0.f;
#pragma unroll
      for (int ht = 0; ht < 2; ht++) {
        const int ha = H_ + wv * 64 + ht * 32 + m32;
        const float aav = agaa_sh[ha], w2a = w2_sh[ha];
#pragma unroll
        for (int jt = 0; jt < 2; jt++)
#pragma unroll
          for (int r = 0; r < 16; r++) {
            const float z = acc[jt][ht][r] + aav;
            sa[jt * 16 + r] = fmaf(fmaxf(z, 0.f), w2a, sa[jt * 16 + r]);
          }
      }
#pragma unroll
      for (int m = 0; m < 32; m++) {
        float v = sa[m];
#pragma unroll
        for (int off = 1; off <= 16; off <<= 1) v += __shfl_xor(v, off, 64);
        sa[m] = v;
      }
      if (m32 == 0) {
#pragma unroll
        for (int jt = 0; jt < 2; jt++)
#pragma unroll
          for (int r = 0; r < 16; r++) {
            const int jl = jt * 32 + (r & 3) + 8 * (r >> 2) + 4 * half32;
            sc_part[4 * NJP + wv * NJP + jl] = sa[jt * 16 + r];
          }
      }
    }
    __syncthreads();
    if (t < NJP) {
      scg_sh[ph * NJP + t] = sc_part[t] + sc_part[NJP + t] + sc_part[2 * NJP + t]
                           + sc_part[3 * NJP + t] + bg2p[0];
      attl_sh[ph * NJP + t] = sc_part[4 * NJP + t] + sc_part[5 * NJP + t]
                            + sc_part[6 * NJP + t] + sc_part[7 * NJP + t] + ba2p[0];
    }
  }
  __syncthreads();

  // ---- top-8 over j: value desc, index asc ----
  for (int k = 0; k < K_; k++) {
    float v = scg_sh[t];
    int idx = t;
#pragma unroll
    for (int off = 32; off > 0; off >>= 1) {
      const float vo = __shfl_down(v, off, 64);
      const int io = __shfl_down(idx, off, 64);
      arg_better(vo, io, v, idx);
    }
    if ((t & 63) == 0) { red_v[t >> 6] = v; red_i[t >> 6] = idx; }
    __syncthreads();
    if (t == 0) {
      float bv = red_v[0];
      int bi = red_i[0];
      for (int w = 1; w < 4; w++) arg_better(red_v[w], red_i[w], bv, bi);
      sel_list[k] = bi;
      scg_sh[bi] = -INFINITY;
    }
    __syncthreads();
  }

  bool selj = false;
#pragma unroll
  for (int k = 0; k < K_; k++) selj = selj || (sel_list[k] == t);

  if (t == 0) {
    float m = -INFINITY;
    for (int k = 0; k < K_; k++) m = fmaxf(m, attl_sh[sel_list[k]]);
    float ssum = 0.f;
    for (int k = 0; k < K_; k++) ssum += expf(attl_sh[sel_list[k]] - m);
    red_v[0] = m;
    red_v[1] = ssum;
  }
  __syncthreads();
  const float att = selj ? expf(attl_sh[t] - red_v[0]) / red_v[1] : 0.f;

  float* __restrict__ ctx_out = out;
  float* __restrict__ gate_out = out + B_ * N_ * D_;
  float* __restrict__ att_out = out + B_ * N_ * D_ + B_ * N_ * N_;

  const int row = (b * N_ + i) * N_;
  gate_out[row + t] = selj ? 1.f : 0.f;
  att_out[row + t] = att;

  __syncthreads();
  attl_sh[t] = att;
  __syncthreads();

  if (t < D_) {
    float acc2 = 0.f;
#pragma unroll
    for (int k = 0; k < K_; k++) {
      const int jj = sel_list[k];
      acc2 = fmaf(attl_sh[jj], s[(b * N_ + jj) * D_ + t], acc2);
    }
    ctx_out[(b * N_ + i) * D_ + t] = acc2;
  }
}

extern "C" void kernel_launch(void* const* d_in, const int* in_sizes, int n_in,
                              void* d_out, int out_size, void* d_ws, size_t ws_size,
                              hipStream_t stream) {
  const float* s   = (const float*)d_in[0];
  const float* Wg1 = (const float*)d_in[1];
  const float* bg1 = (const float*)d_in[2];
  const float* Wg2 = (const float*)d_in[3];
  const float* bg2 = (const float*)d_in[4];
  const float* Wa1 = (const float*)d_in[5];
  const float* ba1 = (const float*)d_in[6];
  const float* Wa2 = (const float*)d_in[7];
  const float* ba2 = (const float*)d_in[8];
  float* out = (float*)d_out;

  float* ws = (float*)d_ws;
  float* Ag = ws;                                        // B*N*H floats
  float* Aa = Ag + B_ * N_ * H_;                         // B*N*H floats
  unsigned short* Shi  = (unsigned short*)(Aa + B_ * N_ * H_);  // B*N*D
  unsigned short* Slo  = Shi + B_ * N_ * D_;
  unsigned short* Wghi = Slo + B_ * N_ * D_;             // 16*8*64*8 = 65536
  unsigned short* Wglo = Wghi + 65536;
  unsigned short* Wahi = Wglo + 65536;

  prep_an<<<dim3(B_ * N_), dim3(256), 0, stream>>>(
      s, Wg1, bg1, Wa1, ba1, Ag, Aa, Shi, Slo);
  prep_sw<<<dim3(128), dim3(64), 0, stream>>>(Wg1, Wa1, Wghi, Wglo, Wahi);
  score_kernel<<<dim3(B_ * N_), dim3(256), 0, stream>>>(
      s, Ag, Aa, Shi, Slo, Wghi, Wglo, Wahi, Wg2, bg2, Wa2, ba2, out);
}

// Round 8
// 253.814 us; speedup vs baseline: 2.1514x; 1.5344x over previous
//
#include <hip/hip_runtime.h>
#include <math.h>

#define B_ 4
#define N_ 256
#define D_ 128
#define H_ 256
#define K_ 8
#define KK 256    // GEMM K = [p (128) | sj (128)]
#define NJP 64    // j per phase (4 phases)

typedef short v8s __attribute__((ext_vector_type(8)));    // 8 bf16 = 4 VGPRs
typedef float v16f __attribute__((ext_vector_type(16)));  // 32x32 MFMA acc

// hi = top-16-bit truncation (x - hi is EXACT); lo = RNE bf16 of remainder.
__device__ inline void split_bf16(float x, unsigned short& hi, unsigned short& lo) {
  unsigned u = __float_as_uint(x);
  unsigned uh = u & 0xFFFF0000u;
  hi = (unsigned short)(uh >> 16);
  float r = x - __uint_as_float(uh);
  unsigned ur = __float_as_uint(r);
  ur += 0x7FFFu + ((ur >> 16) & 1u);
  lo = (unsigned short)(ur >> 16);
}

__global__ __launch_bounds__(256) void prep_an(
    const float* __restrict__ s,
    const float* __restrict__ Wg1, const float* __restrict__ bg1,
    const float* __restrict__ Wa1, const float* __restrict__ ba1,
    float* __restrict__ Ag, float* __restrict__ Aa,
    unsigned short* __restrict__ Shi, unsigned short* __restrict__ Slo) {
  const int b = blockIdx.x >> 8;
  const int n = blockIdx.x & 255;
  const int h = threadIdx.x;
  __shared__ float sh[D_];
  if (h < D_) sh[h] = s[(b * N_ + n) * D_ + h];
  __syncthreads();
  float ag = bg1[h], aa = ba1[h];
#pragma unroll 8
  for (int d = 0; d < D_; d++) {
    ag = fmaf(sh[d], Wg1[d * H_ + h], ag);
    aa = fmaf(sh[d], Wa1[d * H_ + h], aa);
  }
  Ag[(b * N_ + n) * H_ + h] = ag;
  Aa[(b * N_ + n) * H_ + h] = aa;
  if (h < D_) {
    unsigned short x, y;
    split_bf16(sh[h], x, y);
    Shi[(b * N_ + n) * D_ + h] = x;
    Slo[(b * N_ + n) * D_ + h] = y;
  }
}

// ---------------------------------------------------------------------------
// prep_sw: W in MFMA-B fragment order: [ks(16)][tile(8 of 32h)][lane(64)][8].
// In-loop B loads become base + lane*16 (fully coalesced).
// Fragment content: h = T*32 + (l&31), k = ks*16 + (l>>5)*8 + e.
// k<128 -> W1 row 256+k (P part); k>=128 -> W1 row k (sj part).
// ---------------------------------------------------------------------------
__global__ __launch_bounds__(64) void prep_sw(
    const float* __restrict__ Wg1, const float* __restrict__ Wa1,
    unsigned short* __restrict__ Wghi, unsigned short* __restrict__ Wglo,
    unsigned short* __restrict__ Wahi) {
  const int ks = blockIdx.x >> 3;
  const int tile = blockIdx.x & 7;
  const int lane = threadIdx.x;
  const int h = tile * 32 + (lane & 31);
  const int kbase = ks * 16 + (lane >> 5) * 8;
  const int idx0 = (blockIdx.x * 64 + lane) * 8;
#pragma unroll
  for (int e = 0; e < 8; e++) {
    const int k = kbase + e;
    const int f = (k < D_) ? (2 * D_ + k) : k;
    unsigned short x, y;
    split_bf16(Wg1[f * H_ + h], x, y);
    Wghi[idx0 + e] = x;
    Wglo[idx0 + e] = y;
    unsigned short xa, ya;
    split_bf16(Wa1[f * H_ + h], xa, ya);
    Wahi[idx0 + e] = xa;
  }
}

__device__ inline void arg_better(float v2, int i2, float& v, int& idx) {
  if (v2 > v || (v2 == v && i2 < idx)) { v = v2; idx = i2; }
}

// LDS A-tile fragment-order index: j-local jl (0..63), k (0..255)
__device__ inline int a_idx(int jl, int k) {
  return (((jl >> 5) * 16 + (k >> 4)) * 64 + ((k >> 3) & 1) * 32 + (jl & 31)) * 8
         + (k & 7);
}

// ---------------------------------------------------------------------------
// score_kernel v8: v7 layouts, but ks-loops are unroll-2 with ROLLING
// pointers (+= 4096 shorts/iter) so each B stream holds ONE live address
// pair. (v6/v7's full unroll materialized 16 addr pairs per stream -> spill.)
// ---------------------------------------------------------------------------
__global__ __launch_bounds__(256, 2) void score_kernel(
    const float* __restrict__ s,
    const float* __restrict__ Ag, const float* __restrict__ Aa,
    const unsigned short* __restrict__ Shi, const unsigned short* __restrict__ Slo,
    const unsigned short* __restrict__ Wghi, const unsigned short* __restrict__ Wglo,
    const unsigned short* __restrict__ Wahi,
    const float* __restrict__ Wg2, const float* __restrict__ bg2p,
    const float* __restrict__ Wa2, const float* __restrict__ ba2p,
    float* __restrict__ out) {
  const int b = blockIdx.x >> 8;
  const int i = blockIdx.x & 255;
  const int t = threadIdx.x;
  const int wv = t >> 6, lane = t & 63;
  const int m32 = lane & 31, half32 = lane >> 5;

  __shared__ unsigned short a_hi[2 * 16 * 64 * 8];   // 32 KB, frag order
  __shared__ unsigned short a_lo[2 * 16 * 64 * 8];   // 32 KB
  __shared__ float si_sh[D_];
  __shared__ float agaa_sh[2 * H_];
  __shared__ float w2_sh[2 * H_];
  __shared__ float sc_part[8 * NJP];   // [0..3]=gate per wave, [4..7]=att
  __shared__ float scg_sh[N_];
  __shared__ float attl_sh[N_];
  __shared__ float red_v[4];
  __shared__ int red_i[4];
  __shared__ int sel_list[K_];

  if (t < D_) si_sh[t] = s[(b * N_ + i) * D_ + t];
  agaa_sh[t] = Ag[(b * N_ + i) * H_ + t];
  agaa_sh[H_ + t] = Aa[(b * N_ + i) * H_ + t];
  w2_sh[t] = Wg2[t];
  w2_sh[H_ + t] = Wa2[t];

  const int boff0 = ((2 * wv + 0) * 64 + lane) * 8;   // h-tile 2wv
  const int boff1 = ((2 * wv + 1) * 64 + lane) * 8;   // h-tile 2wv+1

#pragma unroll 1
  for (int ph = 0; ph < 4; ph++) {
    __syncthreads();
    // ---- stage A tile (frag order): P hi/lo (k<128) + sj hi/lo (k>=128) ----
    {
      const int jl = t >> 2, kq = t & 3;
      const int jg = b * N_ + ph * NJP + jl;
      const float* srow = s + jg * D_ + kq * 32;
      const float* sic = si_sh + kq * 32;
#pragma unroll
      for (int u = 0; u < 8; u++) {
        const float4 sv = *(const float4*)(srow + u * 4);
        unsigned short h0, h1, h2, h3, l0, l1, l2, l3;
        split_bf16(sic[u * 4 + 0] * sv.x, h0, l0);
        split_bf16(sic[u * 4 + 1] * sv.y, h1, l1);
        split_bf16(sic[u * 4 + 2] * sv.z, h2, l2);
        split_bf16(sic[u * 4 + 3] * sv.w, h3, l3);
        const int idx = a_idx(jl, kq * 32 + u * 4);
        *(unsigned*)(a_hi + idx)     = (unsigned)h0 | ((unsigned)h1 << 16);
        *(unsigned*)(a_hi + idx + 2) = (unsigned)h2 | ((unsigned)h3 << 16);
        *(unsigned*)(a_lo + idx)     = (unsigned)l0 | ((unsigned)l1 << 16);
        *(unsigned*)(a_lo + idx + 2) = (unsigned)l2 | ((unsigned)l3 << 16);
      }
      const unsigned short* shr = Shi + jg * D_ + kq * 32;
      const unsigned short* slr = Slo + jg * D_ + kq * 32;
#pragma unroll
      for (int u = 0; u < 4; u++) {
        const int idx = a_idx(jl, 128 + kq * 32 + u * 8);
        *(v8s*)(a_hi + idx) = *(const v8s*)(shr + u * 8);
        *(v8s*)(a_lo + idx) = *(const v8s*)(slr + u * 8);
      }
    }
    __syncthreads();

    // ================= pass G: gate (split-3), acc 64 regs =================
    {
      v16f acc[2][2];
#pragma unroll
      for (int jt = 0; jt < 2; jt++)
#pragma unroll
        for (int ht = 0; ht < 2; ht++) acc[jt][ht] = (v16f)(0.f);

      // rolling B pointers (one live address pair per stream)
      const unsigned short* ph0 = Wghi + boff0;
      const unsigned short* ph1 = Wghi + boff1;
      const unsigned short* pl0 = Wglo + boff0;
      const unsigned short* pl1 = Wglo + boff1;
      v8s bh[2][2], bl[2][2];
      bh[0][0] = *(const v8s*)ph0;  bh[0][1] = *(const v8s*)ph1;
      bl[0][0] = *(const v8s*)pl0;  bl[0][1] = *(const v8s*)pl1;
      ph0 += 4096; ph1 += 4096; pl0 += 4096; pl1 += 4096;

#pragma unroll 2
      for (int ks = 0; ks < 16; ks++) {
        const int cur = ks & 1, nxt = cur ^ 1;
        // prefetch next ks (last iter reads pad - harmless)
        bh[nxt][0] = *(const v8s*)ph0;  bh[nxt][1] = *(const v8s*)ph1;
        bl[nxt][0] = *(const v8s*)pl0;  bl[nxt][1] = *(const v8s*)pl1;
        ph0 += 4096; ph1 += 4096; pl0 += 4096; pl1 += 4096;
        // A frags direct from LDS
        v8s ah0 = *(const v8s*)(a_hi + (ks) * 512 + lane * 8);
        v8s ah1 = *(const v8s*)(a_hi + (16 + ks) * 512 + lane * 8);
        v8s al0 = *(const v8s*)(a_lo + (ks) * 512 + lane * 8);
        v8s al1 = *(const v8s*)(a_lo + (16 + ks) * 512 + lane * 8);
#pragma unroll
        for (int ht = 0; ht < 2; ht++) {
          acc[0][ht] = __builtin_amdgcn_mfma_f32_32x32x16_bf16(ah0, bh[cur][ht], acc[0][ht], 0, 0, 0);
          acc[0][ht] = __builtin_amdgcn_mfma_f32_32x32x16_bf16(ah0, bl[cur][ht], acc[0][ht], 0, 0, 0);
          acc[0][ht] = __builtin_amdgcn_mfma_f32_32x32x16_bf16(al0, bh[cur][ht], acc[0][ht], 0, 0, 0);
          acc[1][ht] = __builtin_amdgcn_mfma_f32_32x32x16_bf16(ah1, bh[cur][ht], acc[1][ht], 0, 0, 0);
          acc[1][ht] = __builtin_amdgcn_mfma_f32_32x32x16_bf16(ah1, bl[cur][ht], acc[1][ht], 0, 0, 0);
          acc[1][ht] = __builtin_amdgcn_mfma_f32_32x32x16_bf16(al1, bh[cur][ht], acc[1][ht], 0, 0, 0);
        }
      }
      // epilogue G
      float sg[32];
#pragma unroll
      for (int m = 0; m < 32; m++) sg[m] = 0.f;
#pragma unroll
      for (int ht = 0; ht < 2; ht++) {
        const int hg = wv * 64 + ht * 32 + m32;
        const float agv = agaa_sh[hg], w2g = w2_sh[hg];
#pragma unroll
        for (int jt = 0; jt < 2; jt++)
#pragma unroll
          for (int r = 0; r < 16; r++) {
            const float z = acc[jt][ht][r] + agv;
            sg[jt * 16 + r] = fmaf(fmaxf(z, 0.f), w2g, sg[jt * 16 + r]);
          }
      }
#pragma unroll
      for (int m = 0; m < 32; m++) {
        float v = sg[m];
#pragma unroll
        for (int off = 1; off <= 16; off <<= 1) v += __shfl_xor(v, off, 64);
        sg[m] = v;
      }
      if (m32 == 0) {
#pragma unroll
        for (int jt = 0; jt < 2; jt++)
#pragma unroll
          for (int r = 0; r < 16; r++) {
            const int jl = jt * 32 + (r & 3) + 8 * (r >> 2) + 4 * half32;
            sc_part[wv * NJP + jl] = sg[jt * 16 + r];
          }
      }
    }

    // ================= pass A: att (hi-only), acc 64 regs =================
    {
      v16f acc[2][2];
#pragma unroll
      for (int jt = 0; jt < 2; jt++)
#pragma unroll
        for (int ht = 0; ht < 2; ht++) acc[jt][ht] = (v16f)(0.f);

      const unsigned short* pa0 = Wahi + boff0;
      const unsigned short* pa1 = Wahi + boff1;
      v8s bh[2][2];
      bh[0][0] = *(const v8s*)pa0;  bh[0][1] = *(const v8s*)pa1;
      pa0 += 4096; pa1 += 4096;

#pragma unroll 2
      for (int ks = 0; ks < 16; ks++) {
        const int cur = ks & 1, nxt = cur ^ 1;
        bh[nxt][0] = *(const v8s*)pa0;  bh[nxt][1] = *(const v8s*)pa1;
        pa0 += 4096; pa1 += 4096;
        v8s ah0 = *(const v8s*)(a_hi + (ks) * 512 + lane * 8);
        v8s ah1 = *(const v8s*)(a_hi + (16 + ks) * 512 + lane * 8);
#pragma unroll
        for (int ht = 0; ht < 2; ht++) {
          acc[0][ht] = __builtin_amdgcn_mfma_f32_32x32x16_bf16(ah0, bh[cur][ht], acc[0][ht], 0, 0, 0);
          acc[1][ht] = __builtin_amdgcn_mfma_f32_32x32x16_bf16(ah1, bh[cur][ht], acc[1][ht], 0, 0, 0);
        }
      }
      // epilogue A
      float sa[32];
#pragma unroll
      for (int m = 0; m < 32; m++) sa[m] = 0.f;
#pragma unroll
      for (int ht = 0; ht < 2; ht++) {
        const int ha = H_ + wv * 64 + ht * 32 + m32;
        const float aav = agaa_sh[ha], w2a = w2_sh[ha];
#pragma unroll
        for (int jt = 0; jt < 2; jt++)
#pragma unroll
          for (int r = 0; r < 16; r++) {
            const float z = acc[jt][ht][r] + aav;
            sa[jt * 16 + r] = fmaf(fmaxf(z, 0.f), w2a, sa[jt * 16 + r]);
          }
      }
#pragma unroll
      for (int m = 0; m < 32; m++) {
        float v = sa[m];
#pragma unroll
        for (int off = 1; off <= 16; off <<= 1) v += __shfl_xor(v, off, 64);
        sa[m] = v;
      }
      if (m32 == 0) {
#pragma unroll
        for (int jt = 0; jt < 2; jt++)
#pragma unroll
          for (int r = 0; r < 16; r++) {
            const int jl = jt * 32 + (r & 3) + 8 * (r >> 2) + 4 * half32;
            sc_part[4 * NJP + wv * NJP + jl] = sa[jt * 16 + r];
          }
      }
    }
    __syncthreads();
    if (t < NJP) {
      scg_sh[ph * NJP + t] = sc_part[t] + sc_part[NJP + t] + sc_part[2 * NJP + t]
                           + sc_part[3 * NJP + t] + bg2p[0];
      attl_sh[ph * NJP + t] = sc_part[4 * NJP + t] + sc_part[5 * NJP + t]
                            + sc_part[6 * NJP + t] + sc_part[7 * NJP + t] + ba2p[0];
    }
  }
  __syncthreads();

  // ---- top-8 over j: value desc, index asc ----
  for (int k = 0; k < K_; k++) {
    float v = scg_sh[t];
    int idx = t;
#pragma unroll
    for (int off = 32; off > 0; off >>= 1) {
      const float vo = __shfl_down(v, off, 64);
      const int io = __shfl_down(idx, off, 64);
      arg_better(vo, io, v, idx);
    }
    if ((t & 63) == 0) { red_v[t >> 6] = v; red_i[t >> 6] = idx; }
    __syncthreads();
    if (t == 0) {
      float bv = red_v[0];
      int bi = red_i[0];
      for (int w = 1; w < 4; w++) arg_better(red_v[w], red_i[w], bv, bi);
      sel_list[k] = bi;
      scg_sh[bi] = -INFINITY;
    }
    __syncthreads();
  }

  bool selj = false;
#pragma unroll
  for (int k = 0; k < K_; k++) selj = selj || (sel_list[k] == t);

  if (t == 0) {
    float m = -INFINITY;
    for (int k = 0; k < K_; k++) m = fmaxf(m, attl_sh[sel_list[k]]);
    float ssum = 0.f;
    for (int k = 0; k < K_; k++) ssum += expf(attl_sh[sel_list[k]] - m);
    red_v[0] = m;
    red_v[1] = ssum;
  }
  __syncthreads();
  const float att = selj ? expf(attl_sh[t] - red_v[0]) / red_v[1] : 0.f;

  float* __restrict__ ctx_out = out;
  float* __restrict__ gate_out = out + B_ * N_ * D_;
  float* __restrict__ att_out = out + B_ * N_ * D_ + B_ * N_ * N_;

  const int row = (b * N_ + i) * N_;
  gate_out[row + t] = selj ? 1.f : 0.f;
  att_out[row + t] = att;

  __syncthreads();
  attl_sh[t] = att;
  __syncthreads();

  if (t < D_) {
    float acc2 = 0.f;
#pragma unroll
    for (int k = 0; k < K_; k++) {
      const int jj = sel_list[k];
      acc2 = fmaf(attl_sh[jj], s[(b * N_ + jj) * D_ + t], acc2);
    }
    ctx_out[(b * N_ + i) * D_ + t] = acc2;
  }
}

extern "C" void kernel_launch(void* const* d_in, const int* in_sizes, int n_in,
                              void* d_out, int out_size, void* d_ws, size_t ws_size,
                              hipStream_t stream) {
  const float* s   = (const float*)d_in[0];
  const float* Wg1 = (const float*)d_in[1];
  const float* bg1 = (const float*)d_in[2];
  const float* Wg2 = (const float*)d_in[3];
  const float* bg2 = (const float*)d_in[4];
  const float* Wa1 = (const float*)d_in[5];
  const float* ba1 = (const float*)d_in[6];
  const float* Wa2 = (const float*)d_in[7];
  const float* ba2 = (const float*)d_in[8];
  float* out = (float*)d_out;

  float* ws = (float*)d_ws;
  float* Ag = ws;                                        // B*N*H floats
  float* Aa = Ag + B_ * N_ * H_;                         // B*N*H floats
  unsigned short* Shi  = (unsigned short*)(Aa + B_ * N_ * H_);  // B*N*D
  unsigned short* Slo  = Shi + B_ * N_ * D_;
  // W arrays padded by 4096 shorts: last ks-prefetch reads past the end.
  unsigned short* Wghi = Slo + B_ * N_ * D_;             // 65536 + 4096 pad
  unsigned short* Wglo = Wghi + 65536 + 4096;
  unsigned short* Wahi = Wglo + 65536 + 4096;

  prep_an<<<dim3(B_ * N_), dim3(256), 0, stream>>>(
      s, Wg1, bg1, Wa1, ba1, Ag, Aa, Shi, Slo);
  prep_sw<<<dim3(128), dim3(64), 0, stream>>>(Wg1, Wa1, Wghi, Wglo, Wahi);
  score_kernel<<<dim3(B_ * N_), dim3(256), 0, stream>>>(
      s, Ag, Aa, Shi, Slo, Wghi, Wglo, Wahi, Wg2, bg2, Wa2, ba2, out);
}